// Round 11
// baseline (109.719 us; speedup 1.0000x reference)
//
#include <hip/hip_runtime.h>

// FeatureEmbedder: out[b, f*64+d] = relu(x[b,f] * W[f,d] + b[f,d])
// x: [16384, 128] f32, W: [128, 64] f32, b: [128, 64] f32
// out: [16384, 8192] f32  (512 MB -> HBM-write-bound)
//
// R11: 64 write windows + ALL 256 CUs (R10 conflated "64 windows" with
// "64 CUs"; this separates them). 64 groups x 4 blocks x 256 threads.
// Group g owns the contiguous 8 MB region rows [256g, 256g+256); its 4
// blocks interleave at 8-row (256 KB) granules: block k takes granules
// 4i+k, so at step i the group writes the contiguous 1 MB [4i*256KB,+1MB)
// of its window. Device-wide instantaneous footprint ~= 64 windows (the
// stream-count ladder: 512w 102.0 / 256w 102.2 / 64w 99.6 / fill ~1w 78us
// equivalent). Per-block internals = proven R5/R10 structure: 8 hoisted
// W/b pairs, 4 KB x granule double-buffered in LDS (1 load per 64 stores,
// negligible vmcnt coupling), conflict-free 16-lane broadcast ds_reads.

#define BATCH 16384
#define NFEAT 128
#define EMBD  64
#define ROW4  (NFEAT * EMBD / 4)   // 2048 float4 per output row

typedef float vfloat4 __attribute__((ext_vector_type(4)));

__global__ __launch_bounds__(256) void feature_embed_kernel(
    const vfloat4* __restrict__ x4,
    const vfloat4* __restrict__ W4,
    const vfloat4* __restrict__ B4,
    vfloat4* __restrict__ out4) {

    __shared__ float xs[2][8 * NFEAT];    // 2 x 4 KB granule buffers

    const int tid = threadIdx.x;          // 0..255
    const int blk = blockIdx.x;           // 0..255
    const int g   = blk >> 2;             // group, 0..63 (8 MB window each)
    const int k   = blk & 3;              // member within group, 0..3

    // Thread's column for chunk j: col4 = j*256 + tid, j = 0..7. Hoist W/b.
    vfloat4 w[8], bb[8];
    #pragma unroll
    for (int j = 0; j < 8; ++j) {
        w[j]  = W4[j * 256 + tid];
        bb[j] = B4[j * 256 + tid];
    }

    // Granule i (i = 0..7) = x rows 256g + (4i+k)*8 .. +8  (4 KB, 256 float4).
    const int xg0 = 8192 * g + k * 256;   // granule 0 start in float4 units
    ((vfloat4*)xs[0])[tid] = x4[xg0 + tid];
    __syncthreads();

    const int fs = tid >> 4;              // within-chunk feature sub-idx, 0..15

    for (int i = 0; i < 8; ++i) {
        // Prefetch next granule into the other buffer (1 load / 64 stores).
        if (i < 7)
            ((vfloat4*)xs[(i + 1) & 1])[tid] = x4[xg0 + (i + 1) * 1024 + tid];

        const float* xsl = xs[i & 1];
        // Output granule: rows 256g + (4i+k)*8, 8 rows x 32 KB = 256 KB linear.
        vfloat4* outg = out4 + (size_t)(256 * g + (4 * i + k) * 8) * ROW4;

        #pragma unroll 2
        for (int r = 0; r < 8; ++r) {
            const float* xr = xsl + r * NFEAT;
            vfloat4* outr = outg + r * ROW4 + tid;
            #pragma unroll
            for (int j = 0; j < 8; ++j) {
                const float xv = xr[j * 16 + fs];   // ds_read broadcast
                vfloat4 o;
                o.x = fmaxf(fmaf(xv, w[j].x, bb[j].x), 0.0f);
                o.y = fmaxf(fmaf(xv, w[j].y, bb[j].y), 0.0f);
                o.z = fmaxf(fmaf(xv, w[j].z, bb[j].z), 0.0f);
                o.w = fmaxf(fmaf(xv, w[j].w, bb[j].w), 0.0f);
                outr[j * 256] = o;        // next 4 KB of the 256 KB granule
            }
        }
        __syncthreads();  // prefetch visible; old buffer reusable
    }
}

extern "C" void kernel_launch(void* const* d_in, const int* in_sizes, int n_in,
                              void* d_out, int out_size, void* d_ws, size_t ws_size,
                              hipStream_t stream) {
    const vfloat4* x4 = (const vfloat4*)d_in[0];
    const vfloat4* W4 = (const vfloat4*)d_in[1];
    const vfloat4* B4 = (const vfloat4*)d_in[2];
    vfloat4* out4     = (vfloat4*)d_out;

    // 256 blocks x 256 threads; 64 groups of 4 blocks; group g sweeps the
    // contiguous 8 MB window rows [256g, 256g+256) at 256 KB granularity.
    feature_embed_kernel<<<256, 256, 0, stream>>>(x4, W4, B4, out4);
}

// Round 12
// 85.283 us; speedup vs baseline: 1.2865x; 1.2865x over previous
//
#include <hip/hip_runtime.h>

// FeatureEmbedder: out[b, f*64+d] = relu(x[b,f] * W[f,d] + b[f,d])
// x: [16384, 128] f32, W: [128, 64] f32, b: [128, 64] f32
// out: [16384, 8192] f32  (512 MB -> HBM-write-bound)
//
// R12: R10 (best, 99.6 us) + NONTEMPORAL stores — single-variable change.
// Rationale: stores are write-allocated in the per-XCD 4 MB L2; each XCD
// streams 64 MB through it (100% miss/alloc/evict), so DRAM write order is
// the L2 EVICTION order, not store-issue order — explaining why all
// ordering levers (R6/R7/R11) were null: L2 scrambles them. nt stores
// (no-allocate) deliver the crafted linear order to the memory controller.
// R3's nt test was on the SCATTERED layout (preserving a bad order is
// worthless); nt x linear was never tested.
// Structure (= R10): 64 blocks x 1024 threads, block b sweeps a private
// contiguous 8 MB region (rows 256b..+255) in 8 slabs of 32 rows; x slab
// double-buffered in LDS; 2 hoisted W/b pairs; broadcast ds_reads.

#define BATCH 16384
#define NFEAT 128
#define EMBD  64
#define ROW4  (NFEAT * EMBD / 4)   // 2048 float4 per output row

typedef float vfloat4 __attribute__((ext_vector_type(4)));

__global__ __launch_bounds__(1024) void feature_embed_kernel(
    const vfloat4* __restrict__ x4,
    const vfloat4* __restrict__ W4,
    const vfloat4* __restrict__ B4,
    vfloat4* __restrict__ out4) {

    __shared__ float xs[2][32 * NFEAT];   // 2 x 16 KB slab buffers

    const int tid = threadIdx.x;          // 0..1023
    const int b   = blockIdx.x;           // 0..63

    // Thread's columns: col4 = j*1024 + tid, j = 0..1. Hoist W/b.
    vfloat4 wv[2], bv[2];
    wv[0] = W4[tid];        wv[1] = W4[1024 + tid];
    bv[0] = B4[tid];        bv[1] = B4[1024 + tid];

    // Block owns x rows [256b, 256b+256): 8 slabs x 32 rows.
    const vfloat4* xb = x4 + b * (256 * NFEAT / 4);

    ((vfloat4*)xs[0])[tid] = xb[tid];     // stage slab 0
    __syncthreads();

    const int fs = tid >> 4;              // feature sub-index, 0..63
    vfloat4* outb = out4 + b * 256 * ROW4;  // this block's 8 MB region

    for (int s = 0; s < 8; ++s) {
        // Prefetch next slab into the other buffer (overlaps with stores).
        if (s < 7)
            ((vfloat4*)xs[(s + 1) & 1])[tid] = xb[(s + 1) * 1024 + tid];

        const float* xsl = xs[s & 1];
        vfloat4* outs = outb + s * 32 * ROW4;

        #pragma unroll 4
        for (int r = 0; r < 32; ++r) {
            const float* xr = xsl + r * NFEAT;
            vfloat4* outr = outs + r * ROW4 + tid;
            #pragma unroll
            for (int j = 0; j < 2; ++j) {
                const float xv = xr[j * 64 + fs];   // ds_read broadcast
                vfloat4 o;
                o.x = fmaxf(fmaf(xv, wv[j].x, bv[j].x), 0.0f);
                o.y = fmaxf(fmaf(xv, wv[j].y, bv[j].y), 0.0f);
                o.z = fmaxf(fmaf(xv, wv[j].z, bv[j].z), 0.0f);
                o.w = fmaxf(fmaf(xv, wv[j].w, bv[j].w), 0.0f);
                // Streaming store: linear sweep, no L2 allocation.
                __builtin_nontemporal_store(o, &outr[j * 1024]);
            }
        }
        __syncthreads();  // prefetch visible; buffer free for next overwrite
    }
}

extern "C" void kernel_launch(void* const* d_in, const int* in_sizes, int n_in,
                              void* d_out, int out_size, void* d_ws, size_t ws_size,
                              hipStream_t stream) {
    const vfloat4* x4 = (const vfloat4*)d_in[0];
    const vfloat4* W4 = (const vfloat4*)d_in[1];
    const vfloat4* B4 = (const vfloat4*)d_in[2];
    vfloat4* out4     = (vfloat4*)d_out;

    // 64 blocks x 1024 threads; block b writes rows [256b, 256b+256) linearly.
    feature_embed_kernel<<<64, 1024, 0, stream>>>(x4, W4, B4, out4);
}